// Round 4
// baseline (214.819 us; speedup 1.0000x reference)
//
#include <hip/hip_runtime.h>
#include <hip/hip_bf16.h>
#include <stdint.h>

typedef unsigned short u16;
typedef unsigned int u32;
typedef unsigned long long u64;
using bf16x8 = __attribute__((ext_vector_type(8))) __bf16;
using f32x4  = __attribute__((ext_vector_type(4))) float;
using f32x16 = __attribute__((ext_vector_type(16))) float;

static constexpr int B_ = 4, H_ = 8, S_ = 2048, D_ = 64, DM_ = 512;
// 0.125 (1/sqrt(64)) * log2(e): folds softmax exp->exp2 into q projection
#define QSCALE 0.1803368801111601f

__device__ __forceinline__ u16 f2b(float f) {
  u32 u = __float_as_uint(f);
  u = (u + 0x7FFFu + ((u >> 16) & 1u)) >> 16;
  return (u16)u;
}

__device__ __forceinline__ u32 cvtpk_bf16(float a, float b) {
  u32 r;
  asm("v_cvt_pk_bf16_f32 %0, %1, %2" : "=v"(r) : "v"(a), "v"(b));
  return r;
}
__device__ __forceinline__ void plswap(u32& a, u32& b) {
  asm("v_permlane32_swap_b32 %0, %1" : "+v"(a), "+v"(b));
}
#if __has_builtin(__builtin_amdgcn_exp2f)
__device__ __forceinline__ float exp2fast(float x) { return __builtin_amdgcn_exp2f(x); }
#else
__device__ __forceinline__ float exp2fast(float x) {
  float r;
  asm("v_exp_f32 %0, %1" : "=v"(r) : "v"(x));
  return r;
}
#endif

// ---------------- weight prep: W fp32 [k][n] -> Wt bf16 [n][k], 4 weights ----------------
__global__ __launch_bounds__(256) void prep_w_kernel(
    const float* __restrict__ Wq, const float* __restrict__ Wk,
    const float* __restrict__ Wv, const float* __restrict__ Wo,
    u16* __restrict__ Wtq, u16* __restrict__ Wtk, u16* __restrict__ Wtv, u16* __restrict__ Wto) {
  __shared__ float tile[32][33];
  const int z = blockIdx.z;
  const float* W = z == 0 ? Wq : z == 1 ? Wk : z == 2 ? Wv : Wo;
  u16* Wt       = z == 0 ? Wtq : z == 1 ? Wtk : z == 2 ? Wtv : Wto;
  const int k0 = blockIdx.x * 32, n0 = blockIdx.y * 32;
  const int t = threadIdx.x;
  {
    const int kl = t >> 3, nl4 = (t & 7) * 4;
    float4 v = *(const float4*)(W + (size_t)(k0 + kl) * DM_ + n0 + nl4);
    tile[kl][nl4 + 0] = v.x; tile[kl][nl4 + 1] = v.y;
    tile[kl][nl4 + 2] = v.z; tile[kl][nl4 + 3] = v.w;
  }
  __syncthreads();
  {
    const int nl = t >> 3, kl4 = (t & 7) * 4;
    ushort4 o;
    o.x = f2b(tile[kl4 + 0][nl]); o.y = f2b(tile[kl4 + 1][nl]);
    o.z = f2b(tile[kl4 + 2][nl]); o.w = f2b(tile[kl4 + 3][nl]);
    *(ushort4*)(Wt + (size_t)(n0 + nl) * DM_ + k0 + kl4) = o;
  }
}

// ---------------- mask int32 -> bitmask ----------------
__global__ void pack_mask_kernel(const int* __restrict__ mask, u32* __restrict__ bits) {
  int i = blockIdx.x * blockDim.x + threadIdx.x;
  unsigned long long bal = __ballot(mask[i] != 0);
  int lane = threadIdx.x & 63;
  if (lane == 0)       bits[i >> 5] = (u32)bal;
  else if (lane == 32) bits[i >> 5] = (u32)(bal >> 32);
}

// ---------------- fused QKV projection GEMM ----------------
__global__ __launch_bounds__(256) void gemm_qkv_kernel(
    const float* __restrict__ Qf, const float* __restrict__ Kf, const float* __restrict__ Vf,
    const u16* __restrict__ Wtq, const u16* __restrict__ Wtk, const u16* __restrict__ Wtv,
    const float* __restrict__ bq, const float* __restrict__ bk, const float* __restrict__ bv,
    u16* __restrict__ qp, u16* __restrict__ kp, u16* __restrict__ vp) {
  __shared__ u16 As[128][40];
  __shared__ u16 Bs[128][40];
  const int z = blockIdx.z;
  const float* A    = z == 0 ? Qf : z == 1 ? Kf : Vf;
  const u16* Bt     = z == 0 ? Wtq : z == 1 ? Wtk : Wtv;
  const float* bias = z == 0 ? bq : z == 1 ? bk : bv;
  u16* outp         = z == 0 ? qp : z == 1 ? kp : vp;
  const float scale = z == 0 ? QSCALE : 1.0f;

  const int t = threadIdx.x;
  const int lane = t & 63, wid = t >> 6;
  const int wr = wid >> 1, wc = wid & 1;
  const int l15 = lane & 15, l4 = lane >> 4;
  const int cn = blockIdx.x * 128, rm = blockIdx.y * 128;
  const int srow = t >> 2, scol = (t & 3) << 3;

  f32x4 acc[4][4] = {};

  for (int k0 = 0; k0 < DM_; k0 += 32) {
    __syncthreads();
    {
      const float* a0 = A + (size_t)(rm + srow) * DM_ + k0 + scol;
      float4 f0 = *(const float4*)a0, f1 = *(const float4*)(a0 + 4);
      uint4 u;
      u.x = cvtpk_bf16(f0.x, f0.y); u.y = cvtpk_bf16(f0.z, f0.w);
      u.z = cvtpk_bf16(f1.x, f1.y); u.w = cvtpk_bf16(f1.z, f1.w);
      *(uint4*)(&As[srow][scol]) = u;
      const float* a1 = A + (size_t)(rm + srow + 64) * DM_ + k0 + scol;
      float4 g0 = *(const float4*)a1, g1 = *(const float4*)(a1 + 4);
      uint4 w2;
      w2.x = cvtpk_bf16(g0.x, g0.y); w2.y = cvtpk_bf16(g0.z, g0.w);
      w2.z = cvtpk_bf16(g1.x, g1.y); w2.w = cvtpk_bf16(g1.z, g1.w);
      *(uint4*)(&As[srow + 64][scol]) = w2;
    }
    *(uint4*)(&Bs[srow][scol])      = *(const uint4*)(Bt + (size_t)(cn + srow) * DM_ + k0 + scol);
    *(uint4*)(&Bs[srow + 64][scol]) = *(const uint4*)(Bt + (size_t)(cn + srow + 64) * DM_ + k0 + scol);
    __syncthreads();
    bf16x8 af[4], bfr[4];
#pragma unroll
    for (int m = 0; m < 4; ++m)
      af[m] = *(const bf16x8*)(&As[wr * 64 + m * 16 + l15][l4 * 8]);
#pragma unroll
    for (int n = 0; n < 4; ++n)
      bfr[n] = *(const bf16x8*)(&Bs[wc * 64 + n * 16 + l15][l4 * 8]);
#pragma unroll
    for (int m = 0; m < 4; ++m)
#pragma unroll
      for (int n = 0; n < 4; ++n)
        acc[m][n] = __builtin_amdgcn_mfma_f32_16x16x32_bf16(af[m], bfr[n], acc[m][n], 0, 0, 0);
  }

#pragma unroll
  for (int m = 0; m < 4; ++m)
#pragma unroll
    for (int n = 0; n < 4; ++n) {
      int col = cn + wc * 64 + n * 16 + l15;
      float bv_ = bias[col];
#pragma unroll
      for (int r = 0; r < 4; ++r) {
        int row = rm + wr * 64 + m * 16 + l4 * 4 + r;
        float v = (acc[m][n][r] + bv_) * scale;
        int b = row >> 11, s = row & 2047;
        int h = col >> 6, d = col & 63;
        if (z < 2)
          outp[(((size_t)(b * H_ + h)) * S_ + s) * D_ + d] = f2b(v);
        else
          outp[(((size_t)(b * H_ + h)) * D_ + d) * S_ + s] = f2b(v);
      }
    }
}

// ---------------- output GEMM: out[8192][512] fp32 = ctx bf16 @ Wo^T + bo ----------------
__global__ __launch_bounds__(256) void gemm_out_kernel(
    const u16* __restrict__ A, const u16* __restrict__ Bt,
    const float* __restrict__ bias, float* __restrict__ outp) {
  __shared__ u16 As[64][40];
  __shared__ u16 Bs[128][40];
  const int t = threadIdx.x;
  const int lane = t & 63, w = t >> 6;
  const int l15 = lane & 15, l4 = lane >> 4;
  const int cn = blockIdx.x * 128, rm = blockIdx.y * 64;
  const int srow = t >> 2, scol = (t & 3) << 3;

  f32x4 acc[4][2] = {};

  for (int k0 = 0; k0 < DM_; k0 += 32) {
    __syncthreads();
    *(uint4*)(&As[srow][scol])      = *(const uint4*)(A + (size_t)(rm + srow) * DM_ + k0 + scol);
    *(uint4*)(&Bs[srow][scol])      = *(const uint4*)(Bt + (size_t)(cn + srow) * DM_ + k0 + scol);
    *(uint4*)(&Bs[srow + 64][scol]) = *(const uint4*)(Bt + (size_t)(cn + srow + 64) * DM_ + k0 + scol);
    __syncthreads();
    bf16x8 af[4], bfr[2];
#pragma unroll
    for (int m = 0; m < 4; ++m)
      af[m] = *(const bf16x8*)(&As[m * 16 + l15][l4 * 8]);
#pragma unroll
    for (int n = 0; n < 2; ++n)
      bfr[n] = *(const bf16x8*)(&Bs[w * 32 + n * 16 + l15][l4 * 8]);
#pragma unroll
    for (int m = 0; m < 4; ++m)
#pragma unroll
      for (int n = 0; n < 2; ++n)
        acc[m][n] = __builtin_amdgcn_mfma_f32_16x16x32_bf16(af[m], bfr[n], acc[m][n], 0, 0, 0);
  }

#pragma unroll
  for (int m = 0; m < 4; ++m)
#pragma unroll
    for (int n = 0; n < 2; ++n) {
      int col = cn + w * 32 + n * 16 + l15;
      float bv_ = bias[col];
#pragma unroll
      for (int r = 0; r < 4; ++r) {
        int row = rm + m * 16 + l4 * 4 + r;
        outp[(size_t)row * DM_ + col] = acc[m][n][r] + bv_;
      }
    }
}

// ---------------- flash attention: barrier-free, direct-from-L2, split-K2 ----------------
// grid 1024 (XCD-swizzled), 256 threads = 4 waves = {2 q-subtiles x 2 key-halves}.
// Each wave: 32 q-rows x 1024 keys (its half), no LDS staging, no per-tile barrier.
// Exact combine (no-max softmax is linear): one LDS exchange + single barrier.
__global__ __launch_bounds__(256, 4) void attn_kernel(
    const u16* __restrict__ qp, const u16* __restrict__ kp, const u16* __restrict__ vp,
    const u64* __restrict__ mbits, u16* __restrict__ ctx) {
  __shared__ float Ol[2][32][64];  // [qsub][q][d] partials from khalf=1 waves
  __shared__ float Ll[2][32];
  const int t = threadIdx.x, lane = t & 63, w = t >> 6;
  const int l31 = lane & 31, hi = lane >> 5;
  const int qsub = w & 1, khalf = w >> 1;
  // XCD-aware remap: one head per XCD (K/V stay L2-resident)
  const int wgid = blockIdx.x;
  const int h = wgid & 7, idx = wgid >> 3;
  const int b = idx >> 5, qt = idx & 31;
  const size_t head  = ((size_t)(b * H_ + h)) * S_ * D_;
  const size_t headT = ((size_t)(b * H_ + h)) * D_ * S_;
  const int q0 = qt * 64 + qsub * 32;
  const int q  = q0 + l31;

  // Q fragments (B-operand): col q = lane&31, k = ks*16 + hi*8 + j
  bf16x8 qf[4];
  {
    const u16* qrow = qp + head + (size_t)q * D_;
#pragma unroll
    for (int ks = 0; ks < 4; ++ks) qf[ks] = *(const bf16x8*)(qrow + ks * 16 + hi * 8);
  }

  // per-lane global fragment pointers (advance 2 tiles = 128 rows / 128 keys per iter)
  const u16* kp0 = kp + head + ((size_t)khalf * 64 + l31) * D_ + hi * 8;
  const u16* kp1 = kp0 + 32 * D_;
  const u16* vp0 = vp + headT + (size_t)l31 * S_ + khalf * 64 + hi * 8;
  const u16* vp1 = vp0 + (size_t)32 * S_;
  const u64* mp  = mbits + ((size_t)b * S_ + q) * (S_ / 64) + khalf;

  f32x16 accO0, accO1;
#pragma unroll
  for (int i = 0; i < 16; ++i) { accO0[i] = 0.f; accO1[i] = 0.f; }
  float lrow = 0.f;

  for (int it = 0; it < 16; ++it) {
    u64 mw = mp[it * 2] >> (hi * 4);
    const u32 mlo = (u32)mw, mhi = (u32)(mw >> 32);

    // QK^T swapped: S^T[key][q]; K fragments straight from global (L1/L2)
    f32x16 s0, s1;
#pragma unroll
    for (int i = 0; i < 16; ++i) { s0[i] = 0.f; s1[i] = 0.f; }
    {
      bf16x8 kf0[4], kf1[4];
#pragma unroll
      for (int ks = 0; ks < 4; ++ks) kf0[ks] = *(const bf16x8*)(kp0 + ks * 16);
#pragma unroll
      for (int ks = 0; ks < 4; ++ks) kf1[ks] = *(const bf16x8*)(kp1 + ks * 16);
      __builtin_amdgcn_s_setprio(1);
#pragma unroll
      for (int ks = 0; ks < 4; ++ks)
        s0 = __builtin_amdgcn_mfma_f32_32x32x16_bf16(kf0[ks], qf[ks], s0, 0, 0, 0);
#pragma unroll
      for (int ks = 0; ks < 4; ++ks)
        s1 = __builtin_amdgcn_mfma_f32_32x32x16_bf16(kf1[ks], qf[ks], s1, 0, 0, 0);
      __builtin_amdgcn_s_setprio(0);
    }
    kp0 += 128 * D_; kp1 += 128 * D_;

    // no-max softmax: e = mask ? exp2(s) : 0  (q pre-scaled by 0.125*log2e)
    float e[32];
    float rs[4] = {0.f, 0.f, 0.f, 0.f};
#pragma unroll
    for (int c = 0; c < 2; ++c)
#pragma unroll
      for (int r = 0; r < 16; ++r) {
        const int kbit = c * 32 + (r & 3) + 8 * (r >> 2);
        const u32 wsel = (kbit < 32) ? mlo : mhi;
        float ex = exp2fast(c ? s1[r] : s0[r]);
        ex = ((wsel >> (kbit & 31)) & 1u) ? ex : 0.f;
        e[c * 16 + r] = ex;
        rs[r & 3] += ex;
      }
    float rsum = (rs[0] + rs[1]) + (rs[2] + rs[3]);
    rsum += __shfl_xor(rsum, 32);
    lrow += rsum;

    // P -> MFMA A-fragments in-register; V fragments straight from global
#pragma unroll
    for (int c = 0; c < 2; ++c) {
      u32 pw[8];
#pragma unroll
      for (int j = 0; j < 8; ++j)
        pw[j] = cvtpk_bf16(e[c * 16 + 2 * j], e[c * 16 + 2 * j + 1]);
      plswap(pw[0], pw[2]); plswap(pw[1], pw[3]);
      plswap(pw[4], pw[6]); plswap(pw[5], pw[7]);
#pragma unroll
      for (int s = 0; s < 2; ++s) {
        union { u32 wds[4]; bf16x8 v; } pa;
        pa.wds[0] = pw[s * 4 + 0]; pa.wds[1] = pw[s * 4 + 1];
        pa.wds[2] = pw[s * 4 + 2]; pa.wds[3] = pw[s * 4 + 3];
        const int slice = c * 2 + s;
        bf16x8 vf0 = *(const bf16x8*)(vp0 + slice * 16);
        bf16x8 vf1 = *(const bf16x8*)(vp1 + slice * 16);
        __builtin_amdgcn_s_setprio(1);
        accO0 = __builtin_amdgcn_mfma_f32_32x32x16_bf16(pa.v, vf0, accO0, 0, 0, 0);
        accO1 = __builtin_amdgcn_mfma_f32_32x32x16_bf16(pa.v, vf1, accO1, 0, 0, 0);
        __builtin_amdgcn_s_setprio(0);
      }
    }
    vp0 += 128; vp1 += 128;
  }

  // ---- split-K combine: khalf=1 waves publish partials; khalf=0 waves reduce + store
  if (khalf == 1) {
#pragma unroll
    for (int r = 0; r < 16; ++r) {
      const int qr = (r & 3) + 8 * (r >> 2) + 4 * hi;
      Ol[qsub][qr][l31]      = accO0[r];
      Ol[qsub][qr][32 + l31] = accO1[r];
    }
    if (hi == 0) Ll[qsub][l31] = lrow;
  }
  __syncthreads();
  if (khalf == 0) {
    lrow += Ll[qsub][l31];
    float inv = 1.0f / lrow;
    float invr[16];
#pragma unroll
    for (int r = 0; r < 16; ++r) invr[r] = __shfl(inv, (r & 3) + 8 * (r >> 2) + 4 * hi);

    const int colA = h * 64 + l31, colB = h * 64 + 32 + l31;
#pragma unroll
    for (int r = 0; r < 16; ++r) {
      const int qr = (r & 3) + 8 * (r >> 2) + 4 * hi;
      const int row = q0 + qr;
      u16* o = ctx + ((size_t)(b * S_) + row) * DM_;
      o[colA] = f2b((accO0[r] + Ol[qsub][qr][l31])      * invr[r]);
      o[colB] = f2b((accO1[r] + Ol[qsub][qr][32 + l31]) * invr[r]);
    }
  }
}

extern "C" void kernel_launch(void* const* d_in, const int* in_sizes, int n_in,
                              void* d_out, int out_size, void* d_ws, size_t ws_size,
                              hipStream_t stream) {
  const float* Q  = (const float*)d_in[0];
  const float* K  = (const float*)d_in[1];
  const float* V  = (const float*)d_in[2];
  const int* mask = (const int*)d_in[3];
  const float* Wq = (const float*)d_in[4];
  const float* bq = (const float*)d_in[5];
  const float* Wk = (const float*)d_in[6];
  const float* bk = (const float*)d_in[7];
  const float* Wv = (const float*)d_in[8];
  const float* bv = (const float*)d_in[9];
  const float* Wo = (const float*)d_in[10];
  const float* bo = (const float*)d_in[11];

  char* ws = (char*)d_ws;
  size_t off = 0;
  auto alloc = [&](size_t bytes) -> void* {
    void* p = ws + off;
    off += (bytes + 255) & ~(size_t)255;
    return p;
  };
  const size_t act_b = (size_t)B_ * S_ * DM_ * 2;
  u16* Wtq = (u16*)alloc((size_t)DM_ * DM_ * 2);
  u16* Wtk = (u16*)alloc((size_t)DM_ * DM_ * 2);
  u16* Wtv = (u16*)alloc((size_t)DM_ * DM_ * 2);
  u16* Wto = (u16*)alloc((size_t)DM_ * DM_ * 2);
  u32* mbits = (u32*)alloc((size_t)B_ * S_ * (S_ / 32) * 4);
  u16* qp  = (u16*)alloc(act_b);
  u16* kp  = (u16*)alloc(act_b);
  u16* vp  = (u16*)alloc(act_b);
  u16* ctx = (u16*)alloc(act_b);

  prep_w_kernel<<<dim3(16, 16, 4), 256, 0, stream>>>(Wq, Wk, Wv, Wo, Wtq, Wtk, Wtv, Wto);
  pack_mask_kernel<<<(B_ * S_ * S_) / 256, 256, 0, stream>>>(mask, mbits);

  gemm_qkv_kernel<<<dim3(4, 64, 3), 256, 0, stream>>>(
      Q, K, V, Wtq, Wtk, Wtv, bq, bk, bv, qp, kp, vp);

  attn_kernel<<<dim3(1024), 256, 0, stream>>>(qp, kp, vp, (const u64*)mbits, ctx);

  gemm_out_kernel<<<dim3(4, 128), 256, 0, stream>>>(ctx, Wto, bo, (float*)d_out);
}

// Round 5
// 146.595 us; speedup vs baseline: 1.4654x; 1.4654x over previous
//
#include <hip/hip_runtime.h>
#include <hip/hip_bf16.h>
#include <stdint.h>

typedef unsigned short u16;
typedef unsigned int u32;
typedef unsigned long long u64;
using bf16x8 = __attribute__((ext_vector_type(8))) __bf16;
using f32x4  = __attribute__((ext_vector_type(4))) float;
using f32x16 = __attribute__((ext_vector_type(16))) float;

static constexpr int B_ = 4, H_ = 8, S_ = 2048, D_ = 64, DM_ = 512;
// 0.125 (1/sqrt(64)) * log2(e): folds softmax exp->exp2 into q projection
#define QSCALE 0.1803368801111601f

__device__ __forceinline__ u16 f2b(float f) {
  u32 u = __float_as_uint(f);
  u = (u + 0x7FFFu + ((u >> 16) & 1u)) >> 16;
  return (u16)u;
}

__device__ __forceinline__ u32 cvtpk_bf16(float a, float b) {
  u32 r;
  asm("v_cvt_pk_bf16_f32 %0, %1, %2" : "=v"(r) : "v"(a), "v"(b));
  return r;
}
__device__ __forceinline__ void plswap(u32& a, u32& b) {
  asm("v_permlane32_swap_b32 %0, %1" : "+v"(a), "+v"(b));
}
__device__ __forceinline__ void gload16(const void* g, void* lds) {
  __builtin_amdgcn_global_load_lds(
      (const __attribute__((address_space(1))) u32*)g,
      (__attribute__((address_space(3))) u32*)lds, 16, 0, 0);
}
#if __has_builtin(__builtin_amdgcn_exp2f)
__device__ __forceinline__ float exp2fast(float x) { return __builtin_amdgcn_exp2f(x); }
#else
__device__ __forceinline__ float exp2fast(float x) {
  float r;
  asm("v_exp_f32 %0, %1" : "=v"(r) : "v"(x));
  return r;
}
#endif

// ---------------- weight prep: W fp32 [k][n] -> Wt bf16 [n][k], 4 weights ----------------
__global__ __launch_bounds__(256) void prep_w_kernel(
    const float* __restrict__ Wq, const float* __restrict__ Wk,
    const float* __restrict__ Wv, const float* __restrict__ Wo,
    u16* __restrict__ Wtq, u16* __restrict__ Wtk, u16* __restrict__ Wtv, u16* __restrict__ Wto) {
  __shared__ float tile[32][33];
  const int z = blockIdx.z;
  const float* W = z == 0 ? Wq : z == 1 ? Wk : z == 2 ? Wv : Wo;
  u16* Wt       = z == 0 ? Wtq : z == 1 ? Wtk : z == 2 ? Wtv : Wto;
  const int k0 = blockIdx.x * 32, n0 = blockIdx.y * 32;
  const int t = threadIdx.x;
  {
    const int kl = t >> 3, nl4 = (t & 7) * 4;
    float4 v = *(const float4*)(W + (size_t)(k0 + kl) * DM_ + n0 + nl4);
    tile[kl][nl4 + 0] = v.x; tile[kl][nl4 + 1] = v.y;
    tile[kl][nl4 + 2] = v.z; tile[kl][nl4 + 3] = v.w;
  }
  __syncthreads();
  {
    const int nl = t >> 3, kl4 = (t & 7) * 4;
    ushort4 o;
    o.x = f2b(tile[kl4 + 0][nl]); o.y = f2b(tile[kl4 + 1][nl]);
    o.z = f2b(tile[kl4 + 2][nl]); o.w = f2b(tile[kl4 + 3][nl]);
    *(ushort4*)(Wt + (size_t)(n0 + nl) * DM_ + k0 + kl4) = o;
  }
}

// ---------------- mask int32 -> bitmask ----------------
__global__ void pack_mask_kernel(const int* __restrict__ mask, u32* __restrict__ bits) {
  int i = blockIdx.x * blockDim.x + threadIdx.x;
  unsigned long long bal = __ballot(mask[i] != 0);
  int lane = threadIdx.x & 63;
  if (lane == 0)       bits[i >> 5] = (u32)bal;
  else if (lane == 32) bits[i >> 5] = (u32)(bal >> 32);
}

// ---------------- fused QKV projection GEMM ----------------
__global__ __launch_bounds__(256) void gemm_qkv_kernel(
    const float* __restrict__ Qf, const float* __restrict__ Kf, const float* __restrict__ Vf,
    const u16* __restrict__ Wtq, const u16* __restrict__ Wtk, const u16* __restrict__ Wtv,
    const float* __restrict__ bq, const float* __restrict__ bk, const float* __restrict__ bv,
    u16* __restrict__ qp, u16* __restrict__ kp, u16* __restrict__ vp) {
  __shared__ u16 As[128][40];
  __shared__ u16 Bs[128][40];
  const int z = blockIdx.z;
  const float* A    = z == 0 ? Qf : z == 1 ? Kf : Vf;
  const u16* Bt     = z == 0 ? Wtq : z == 1 ? Wtk : Wtv;
  const float* bias = z == 0 ? bq : z == 1 ? bk : bv;
  u16* outp         = z == 0 ? qp : z == 1 ? kp : vp;
  const float scale = z == 0 ? QSCALE : 1.0f;

  const int t = threadIdx.x;
  const int lane = t & 63, wid = t >> 6;
  const int wr = wid >> 1, wc = wid & 1;
  const int l15 = lane & 15, l4 = lane >> 4;
  const int cn = blockIdx.x * 128, rm = blockIdx.y * 128;
  const int srow = t >> 2, scol = (t & 3) << 3;

  f32x4 acc[4][4] = {};

  for (int k0 = 0; k0 < DM_; k0 += 32) {
    __syncthreads();
    {
      const float* a0 = A + (size_t)(rm + srow) * DM_ + k0 + scol;
      float4 f0 = *(const float4*)a0, f1 = *(const float4*)(a0 + 4);
      uint4 u;
      u.x = cvtpk_bf16(f0.x, f0.y); u.y = cvtpk_bf16(f0.z, f0.w);
      u.z = cvtpk_bf16(f1.x, f1.y); u.w = cvtpk_bf16(f1.z, f1.w);
      *(uint4*)(&As[srow][scol]) = u;
      const float* a1 = A + (size_t)(rm + srow + 64) * DM_ + k0 + scol;
      float4 g0 = *(const float4*)a1, g1 = *(const float4*)(a1 + 4);
      uint4 w2;
      w2.x = cvtpk_bf16(g0.x, g0.y); w2.y = cvtpk_bf16(g0.z, g0.w);
      w2.z = cvtpk_bf16(g1.x, g1.y); w2.w = cvtpk_bf16(g1.z, g1.w);
      *(uint4*)(&As[srow + 64][scol]) = w2;
    }
    *(uint4*)(&Bs[srow][scol])      = *(const uint4*)(Bt + (size_t)(cn + srow) * DM_ + k0 + scol);
    *(uint4*)(&Bs[srow + 64][scol]) = *(const uint4*)(Bt + (size_t)(cn + srow + 64) * DM_ + k0 + scol);
    __syncthreads();
    bf16x8 af[4], bfr[4];
#pragma unroll
    for (int m = 0; m < 4; ++m)
      af[m] = *(const bf16x8*)(&As[wr * 64 + m * 16 + l15][l4 * 8]);
#pragma unroll
    for (int n = 0; n < 4; ++n)
      bfr[n] = *(const bf16x8*)(&Bs[wc * 64 + n * 16 + l15][l4 * 8]);
#pragma unroll
    for (int m = 0; m < 4; ++m)
#pragma unroll
      for (int n = 0; n < 4; ++n)
        acc[m][n] = __builtin_amdgcn_mfma_f32_16x16x32_bf16(af[m], bfr[n], acc[m][n], 0, 0, 0);
  }

#pragma unroll
  for (int m = 0; m < 4; ++m)
#pragma unroll
    for (int n = 0; n < 4; ++n) {
      int col = cn + wc * 64 + n * 16 + l15;
      float bv_ = bias[col];
#pragma unroll
      for (int r = 0; r < 4; ++r) {
        int row = rm + wr * 64 + m * 16 + l4 * 4 + r;
        float v = (acc[m][n][r] + bv_) * scale;
        int b = row >> 11, s = row & 2047;
        int h = col >> 6, d = col & 63;
        if (z < 2)
          outp[(((size_t)(b * H_ + h)) * S_ + s) * D_ + d] = f2b(v);
        else
          outp[(((size_t)(b * H_ + h)) * D_ + d) * S_ + s] = f2b(v);
      }
    }
}

// ---------------- output GEMM: out[8192][512] fp32 = ctx bf16 @ Wo^T + bo ----------------
__global__ __launch_bounds__(256) void gemm_out_kernel(
    const u16* __restrict__ A, const u16* __restrict__ Bt,
    const float* __restrict__ bias, float* __restrict__ outp) {
  __shared__ u16 As[64][40];
  __shared__ u16 Bs[128][40];
  const int t = threadIdx.x;
  const int lane = t & 63, w = t >> 6;
  const int l15 = lane & 15, l4 = lane >> 4;
  const int cn = blockIdx.x * 128, rm = blockIdx.y * 64;
  const int srow = t >> 2, scol = (t & 3) << 3;

  f32x4 acc[4][2] = {};

  for (int k0 = 0; k0 < DM_; k0 += 32) {
    __syncthreads();
    *(uint4*)(&As[srow][scol])      = *(const uint4*)(A + (size_t)(rm + srow) * DM_ + k0 + scol);
    *(uint4*)(&Bs[srow][scol])      = *(const uint4*)(Bt + (size_t)(cn + srow) * DM_ + k0 + scol);
    *(uint4*)(&Bs[srow + 64][scol]) = *(const uint4*)(Bt + (size_t)(cn + srow + 64) * DM_ + k0 + scol);
    __syncthreads();
    bf16x8 af[4], bfr[2];
#pragma unroll
    for (int m = 0; m < 4; ++m)
      af[m] = *(const bf16x8*)(&As[m * 16 + l15][l4 * 8]);
#pragma unroll
    for (int n = 0; n < 2; ++n)
      bfr[n] = *(const bf16x8*)(&Bs[w * 32 + n * 16 + l15][l4 * 8]);
#pragma unroll
    for (int m = 0; m < 4; ++m)
#pragma unroll
      for (int n = 0; n < 2; ++n)
        acc[m][n] = __builtin_amdgcn_mfma_f32_16x16x32_bf16(af[m], bfr[n], acc[m][n], 0, 0, 0);
  }

#pragma unroll
  for (int m = 0; m < 4; ++m)
#pragma unroll
    for (int n = 0; n < 2; ++n) {
      int col = cn + w * 32 + n * 16 + l15;
      float bv_ = bias[col];
#pragma unroll
      for (int r = 0; r < 4; ++r) {
        int row = rm + m * 16 + l4 * 4 + r;
        outp[(size_t)row * DM_ + col] = acc[m][n][r] + bv_;
      }
    }
}

// ---------------- flash attention: LDS-staged, in-block split-K2 ----------------
// grid 1024 (XCD head-pinned), 256 threads = 4 waves = {2 q-subtiles x 2 key-halves}.
// Block: q-tile 64, KV tiles of 64 keys staged via global_load_lds (dbuf, XOR-swizzled);
// wave (qsub,ksub) computes 32q x keys[ksub*32..+32) of each tile. Exact combine at end
// (no-max softmax is linear): one LDS exchange aliased onto the staging buffers.
__global__ __launch_bounds__(256, 4) void attn_kernel(
    const u16* __restrict__ qp, const u16* __restrict__ kp, const u16* __restrict__ vp,
    const u64* __restrict__ mbits, u16* __restrict__ ctx) {
  __shared__ __align__(16) char smem[32768];  // [0,16K): Kl[2][64][64]; [16K,32K): Vl[2][64][64]
  const int t = threadIdx.x, lane = t & 63, w = t >> 6;
  const int l31 = lane & 31, hi = lane >> 5;
  const int ksub = w & 1, qsub = w >> 1;
  // XCD-aware remap: one head per XCD (K/V stay L2-resident)
  const int wgid = blockIdx.x;
  const int h = wgid & 7, idx = wgid >> 3;
  const int b = idx >> 5, qt = idx & 31;
  const size_t head  = ((size_t)(b * H_ + h)) * S_ * D_;
  const size_t headT = ((size_t)(b * H_ + h)) * D_ * S_;
  const int q0 = qt * 64 + qsub * 32;
  const int q  = q0 + l31;

  // Q fragments (B-operand): col q = lane&31, k = ks*16 + hi*8 + j
  bf16x8 qf[4];
  {
    const u16* qrow = qp + head + (size_t)q * D_;
#pragma unroll
    for (int ks = 0; ks < 4; ++ks) qf[ks] = *(const bf16x8*)(qrow + ks * 16 + hi * 8);
  }

  // LDS read addressing: byte = row*128 + (colbyte ^ ((row&7)<<4))
  const int kxor = (l31 & 7) << 4;
  const int krbase = (ksub * 32 + l31) * 128;          // K rows: this wave's 32 keys
  const int rbase0 = l31 * 128, rbase1 = (32 + l31) * 128;  // V rows: d, 32+d
  int colx[4];
#pragma unroll
  for (int s = 0; s < 4; ++s) colx[s] = ((s * 32 + hi * 16) ^ kxor);
  int vcolx[2];
#pragma unroll
  for (int s = 0; s < 2; ++s) vcolx[s] = ((ksub * 64 + s * 32 + hi * 16) ^ kxor);

  // staging: 4 x gload16 per thread per tile; LDS dest linear, global col pre-swizzled
  const int srow = lane >> 3;
  const int scol = ((lane & 7) ^ srow) << 3;
  const int c0 = w, c1 = w + 4;
  const u16* ksrc0 = kp + head + (size_t)(c0 * 8 + srow) * D_ + scol;
  const u16* ksrc1 = kp + head + (size_t)(c1 * 8 + srow) * D_ + scol;
  const u16* vsrc0 = vp + headT + (size_t)(c0 * 8 + srow) * S_ + scol;
  const u16* vsrc1 = vp + headT + (size_t)(c1 * 8 + srow) * S_ + scol;

  f32x16 accO0, accO1;
#pragma unroll
  for (int i = 0; i < 16; ++i) { accO0[i] = 0.f; accO1[i] = 0.f; }
  float lrow = 0.f;

  const u64* mrowp = mbits + ((size_t)b * S_ + q) * (S_ / 64);

  auto stage = [&](int bufi, int kt) {
    char* kb = smem + bufi * 8192;
    char* vb = smem + 16384 + bufi * 8192;
    gload16(ksrc0 + (size_t)kt * 4096, kb + c0 * 1024);
    gload16(ksrc1 + (size_t)kt * 4096, kb + c1 * 1024);
    gload16(vsrc0 + kt * 64, vb + c0 * 1024);
    gload16(vsrc1 + kt * 64, vb + c1 * 1024);
  };

  stage(0, 0);
  __syncthreads();
  int buf = 0;

  for (int kt = 0; kt < S_ / 64; ++kt) {
    if (kt < S_ / 64 - 1) stage(buf ^ 1, kt + 1);
    const u32 m32 = (u32)(mrowp[kt] >> (ksub * 32 + hi * 4));

    const char* kb = smem + buf * 8192;
    const char* vb = smem + 16384 + buf * 8192;

    // QK^T swapped: lane holds scores for its q across this wave's 32 keys
    f32x16 s;
#pragma unroll
    for (int i = 0; i < 16; ++i) s[i] = 0.f;
    {
      bf16x8 kf[4];
#pragma unroll
      for (int ks = 0; ks < 4; ++ks) kf[ks] = *(const bf16x8*)(kb + krbase + colx[ks]);
      __builtin_amdgcn_s_setprio(1);
#pragma unroll
      for (int ks = 0; ks < 4; ++ks)
        s = __builtin_amdgcn_mfma_f32_32x32x16_bf16(kf[ks], qf[ks], s, 0, 0, 0);
      __builtin_amdgcn_s_setprio(0);
    }

    // no-max softmax: e = mask ? exp2(s) : 0  (q pre-scaled by 0.125*log2e)
    float e[16];
    float rs[4] = {0.f, 0.f, 0.f, 0.f};
#pragma unroll
    for (int r = 0; r < 16; ++r) {
      const int kbit = (r & 3) + 8 * (r >> 2);
      float ex = exp2fast(s[r]);
      ex = ((m32 >> kbit) & 1u) ? ex : 0.f;
      e[r] = ex;
      rs[r & 3] += ex;
    }
    float rsum = (rs[0] + rs[1]) + (rs[2] + rs[3]);
    rsum += __shfl_xor(rsum, 32);
    lrow += rsum;

    // P -> MFMA A-fragments in-register: cvt_pk + permlane32_swap
    {
      u32 pw[8];
#pragma unroll
      for (int j = 0; j < 8; ++j)
        pw[j] = cvtpk_bf16(e[2 * j], e[2 * j + 1]);
      plswap(pw[0], pw[2]); plswap(pw[1], pw[3]);
      plswap(pw[4], pw[6]); plswap(pw[5], pw[7]);
      __builtin_amdgcn_s_setprio(1);
#pragma unroll
      for (int s2 = 0; s2 < 2; ++s2) {
        union { u32 wds[4]; bf16x8 v; } pa;
        pa.wds[0] = pw[s2 * 4 + 0]; pa.wds[1] = pw[s2 * 4 + 1];
        pa.wds[2] = pw[s2 * 4 + 2]; pa.wds[3] = pw[s2 * 4 + 3];
        bf16x8 vf0 = *(const bf16x8*)(vb + rbase0 + vcolx[s2]);
        accO0 = __builtin_amdgcn_mfma_f32_32x32x16_bf16(pa.v, vf0, accO0, 0, 0, 0);
        bf16x8 vf1 = *(const bf16x8*)(vb + rbase1 + vcolx[s2]);
        accO1 = __builtin_amdgcn_mfma_f32_32x32x16_bf16(pa.v, vf1, accO1, 0, 0, 0);
      }
      __builtin_amdgcn_s_setprio(0);
    }
    __syncthreads();
    buf ^= 1;
  }

  // ---- split-K combine (aliased onto staging LDS, safe after final barrier) ----
  float (*Ol)[32][64] = (float (*)[32][64])smem;        // [qsub][q][d] 16KB
  float* Ll = (float*)(smem + 16384);                   // [qsub*32+q]
  if (ksub == 1) {
#pragma unroll
    for (int r = 0; r < 16; ++r) {
      const int qr = (r & 3) + 8 * (r >> 2) + 4 * hi;
      Ol[qsub][qr][l31]      = accO0[r];
      Ol[qsub][qr][32 + l31] = accO1[r];
    }
    if (hi == 0) Ll[qsub * 32 + l31] = lrow;
  }
  __syncthreads();
  if (ksub == 0) {
    lrow += Ll[qsub * 32 + l31];
    float inv = 1.0f / lrow;
    float invr[16];
#pragma unroll
    for (int r = 0; r < 16; ++r) invr[r] = __shfl(inv, (r & 3) + 8 * (r >> 2) + 4 * hi);

    const int colA = h * 64 + l31, colB = h * 64 + 32 + l31;
#pragma unroll
    for (int r = 0; r < 16; ++r) {
      const int qr = (r & 3) + 8 * (r >> 2) + 4 * hi;
      const int row = q0 + qr;
      u16* o = ctx + ((size_t)(b * S_) + row) * DM_;
      o[colA] = f2b((accO0[r] + Ol[qsub][qr][l31])      * invr[r]);
      o[colB] = f2b((accO1[r] + Ol[qsub][qr][32 + l31]) * invr[r]);
    }
  }
}

extern "C" void kernel_launch(void* const* d_in, const int* in_sizes, int n_in,
                              void* d_out, int out_size, void* d_ws, size_t ws_size,
                              hipStream_t stream) {
  const float* Q  = (const float*)d_in[0];
  const float* K  = (const float*)d_in[1];
  const float* V  = (const float*)d_in[2];
  const int* mask = (const int*)d_in[3];
  const float* Wq = (const float*)d_in[4];
  const float* bq = (const float*)d_in[5];
  const float* Wk = (const float*)d_in[6];
  const float* bk = (const float*)d_in[7];
  const float* Wv = (const float*)d_in[8];
  const float* bv = (const float*)d_in[9];
  const float* Wo = (const float*)d_in[10];
  const float* bo = (const float*)d_in[11];

  char* ws = (char*)d_ws;
  size_t off = 0;
  auto alloc = [&](size_t bytes) -> void* {
    void* p = ws + off;
    off += (bytes + 255) & ~(size_t)255;
    return p;
  };
  const size_t act_b = (size_t)B_ * S_ * DM_ * 2;
  u16* Wtq = (u16*)alloc((size_t)DM_ * DM_ * 2);
  u16* Wtk = (u16*)alloc((size_t)DM_ * DM_ * 2);
  u16* Wtv = (u16*)alloc((size_t)DM_ * DM_ * 2);
  u16* Wto = (u16*)alloc((size_t)DM_ * DM_ * 2);
  u32* mbits = (u32*)alloc((size_t)B_ * S_ * (S_ / 32) * 4);
  u16* qp  = (u16*)alloc(act_b);
  u16* kp  = (u16*)alloc(act_b);
  u16* vp  = (u16*)alloc(act_b);
  u16* ctx = (u16*)alloc(act_b);

  prep_w_kernel<<<dim3(16, 16, 4), 256, 0, stream>>>(Wq, Wk, Wv, Wo, Wtq, Wtk, Wtv, Wto);
  pack_mask_kernel<<<(B_ * S_ * S_) / 256, 256, 0, stream>>>(mask, mbits);

  gemm_qkv_kernel<<<dim3(4, 64, 3), 256, 0, stream>>>(
      Q, K, V, Wtq, Wtk, Wtv, bq, bk, bv, qp, kp, vp);

  attn_kernel<<<dim3(1024), 256, 0, stream>>>(qp, kp, vp, (const u64*)mbits, ctx);

  gemm_out_kernel<<<dim3(4, 128), 256, 0, stream>>>(ctx, Wto, bo, (float*)d_out);
}

// Round 6
// 129.094 us; speedup vs baseline: 1.6640x; 1.1356x over previous
//
#include <hip/hip_runtime.h>
#include <hip/hip_bf16.h>
#include <stdint.h>

typedef unsigned short u16;
typedef unsigned int u32;
typedef unsigned long long u64;
using bf16x8 = __attribute__((ext_vector_type(8))) __bf16;
using f32x4  = __attribute__((ext_vector_type(4))) float;
using f32x16 = __attribute__((ext_vector_type(16))) float;

static constexpr int B_ = 4, H_ = 8, S_ = 2048, D_ = 64, DM_ = 512;
// 0.125 (1/sqrt(64)) * log2(e): folds softmax exp->exp2 into q projection
#define QSCALE 0.1803368801111601f

__device__ __forceinline__ u16 f2b(float f) {
  u32 u = __float_as_uint(f);
  u = (u + 0x7FFFu + ((u >> 16) & 1u)) >> 16;
  return (u16)u;
}

__device__ __forceinline__ u32 cvtpk_bf16(float a, float b) {
  u32 r;
  asm("v_cvt_pk_bf16_f32 %0, %1, %2" : "=v"(r) : "v"(a), "v"(b));
  return r;
}
__device__ __forceinline__ void plswap(u32& a, u32& b) {
  asm("v_permlane32_swap_b32 %0, %1" : "+v"(a), "+v"(b));
}
__device__ __forceinline__ void gload16(const void* g, void* lds) {
  __builtin_amdgcn_global_load_lds(
      (const __attribute__((address_space(1))) u32*)g,
      (__attribute__((address_space(3))) u32*)lds, 16, 0, 0);
}
#if __has_builtin(__builtin_amdgcn_exp2f)
__device__ __forceinline__ float exp2fast(float x) { return __builtin_amdgcn_exp2f(x); }
#else
__device__ __forceinline__ float exp2fast(float x) {
  float r;
  asm("v_exp_f32 %0, %1" : "=v"(r) : "v"(x));
  return r;
}
#endif
// e = pred[lane] ? ex : 0  (predicate in SGPR pair -> 1 VALU op)
__device__ __forceinline__ float selmask(float ex, u64 pred) {
  float r;
  asm("v_cndmask_b32 %0, 0, %1, %2" : "=v"(r) : "v"(ex), "s"(pred));
  return r;
}

// ---------------- weight prep: W fp32 [k][n] -> Wt bf16 [n][k], 4 weights ----------------
__global__ __launch_bounds__(256) void prep_w_kernel(
    const float* __restrict__ Wq, const float* __restrict__ Wk,
    const float* __restrict__ Wv, const float* __restrict__ Wo,
    u16* __restrict__ Wtq, u16* __restrict__ Wtk, u16* __restrict__ Wtv, u16* __restrict__ Wto) {
  __shared__ float tile[32][33];
  const int z = blockIdx.z;
  const float* W = z == 0 ? Wq : z == 1 ? Wk : z == 2 ? Wv : Wo;
  u16* Wt       = z == 0 ? Wtq : z == 1 ? Wtk : z == 2 ? Wtv : Wto;
  const int k0 = blockIdx.x * 32, n0 = blockIdx.y * 32;
  const int t = threadIdx.x;
  {
    const int kl = t >> 3, nl4 = (t & 7) * 4;
    float4 v = *(const float4*)(W + (size_t)(k0 + kl) * DM_ + n0 + nl4);
    tile[kl][nl4 + 0] = v.x; tile[kl][nl4 + 1] = v.y;
    tile[kl][nl4 + 2] = v.z; tile[kl][nl4 + 3] = v.w;
  }
  __syncthreads();
  {
    const int nl = t >> 3, kl4 = (t & 7) * 4;
    ushort4 o;
    o.x = f2b(tile[kl4 + 0][nl]); o.y = f2b(tile[kl4 + 1][nl]);
    o.z = f2b(tile[kl4 + 2][nl]); o.w = f2b(tile[kl4 + 3][nl]);
    *(ushort4*)(Wt + (size_t)(n0 + nl) * DM_ + k0 + kl4) = o;
  }
}

// ---------------- mask -> per-wave lane-predicate words ----------------
// word(b, qg, kt, ksub, r): bit l31      = mask[b][qg*32+l31][kt*64 + ksub*32 + klo(r)]
//                           bit 32+l31   = same at key+4        (klo = (r&3)+8*(r>>2))
// grid (8 kt-groups, 64 qg, 4 b), 256 thr = 4 waves; wave handles one kt (32x64 mask block).
__global__ __launch_bounds__(256) void pack_mask_kernel(const int* __restrict__ mask,
                                                        u64* __restrict__ wmask) {
  __shared__ int mt[4][32][65];
  const int t = threadIdx.x, lane = t & 63, w = t >> 6;
  const int kt = blockIdx.x * 4 + w, qg = blockIdx.y, b = blockIdx.z;
  const int q0 = qg * 32;
  const int* src = mask + ((size_t)b * S_ + q0) * S_ + kt * 64 + lane;
#pragma unroll 8
  for (int i = 0; i < 32; ++i) mt[w][i][lane] = src[(size_t)i * S_];
  // same-wave LDS RAW: compiler inserts lgkmcnt waits; no cross-wave sharing.
  u64* dst = wmask + (((size_t)(b * 64 + qg) * 32 + kt) * 32);
  const int hi4 = (lane >> 5) * 4;
#pragma unroll
  for (int idx = 0; idx < 32; ++idx) {
    const int ksub = idx >> 4, r = idx & 15;
    const int key = ksub * 32 + (r & 3) + 8 * (r >> 2) + hi4;
    u64 bal = __ballot(mt[w][lane & 31][key] != 0);
    if (lane == 0) dst[idx] = bal;
  }
}

// ---------------- fused QKV projection GEMM ----------------
__global__ __launch_bounds__(256) void gemm_qkv_kernel(
    const float* __restrict__ Qf, const float* __restrict__ Kf, const float* __restrict__ Vf,
    const u16* __restrict__ Wtq, const u16* __restrict__ Wtk, const u16* __restrict__ Wtv,
    const float* __restrict__ bq, const float* __restrict__ bk, const float* __restrict__ bv,
    u16* __restrict__ qp, u16* __restrict__ kp, u16* __restrict__ vp) {
  __shared__ u16 As[128][40];
  __shared__ u16 Bs[128][40];
  const int z = blockIdx.z;
  const float* A    = z == 0 ? Qf : z == 1 ? Kf : Vf;
  const u16* Bt     = z == 0 ? Wtq : z == 1 ? Wtk : Wtv;
  const float* bias = z == 0 ? bq : z == 1 ? bk : bv;
  u16* outp         = z == 0 ? qp : z == 1 ? kp : vp;
  const float scale = z == 0 ? QSCALE : 1.0f;

  const int t = threadIdx.x;
  const int lane = t & 63, wid = t >> 6;
  const int wr = wid >> 1, wc = wid & 1;
  const int l15 = lane & 15, l4 = lane >> 4;
  const int cn = blockIdx.x * 128, rm = blockIdx.y * 128;
  const int srow = t >> 2, scol = (t & 3) << 3;

  f32x4 acc[4][4] = {};

  for (int k0 = 0; k0 < DM_; k0 += 32) {
    __syncthreads();
    {
      const float* a0 = A + (size_t)(rm + srow) * DM_ + k0 + scol;
      float4 f0 = *(const float4*)a0, f1 = *(const float4*)(a0 + 4);
      uint4 u;
      u.x = cvtpk_bf16(f0.x, f0.y); u.y = cvtpk_bf16(f0.z, f0.w);
      u.z = cvtpk_bf16(f1.x, f1.y); u.w = cvtpk_bf16(f1.z, f1.w);
      *(uint4*)(&As[srow][scol]) = u;
      const float* a1 = A + (size_t)(rm + srow + 64) * DM_ + k0 + scol;
      float4 g0 = *(const float4*)a1, g1 = *(const float4*)(a1 + 4);
      uint4 w2;
      w2.x = cvtpk_bf16(g0.x, g0.y); w2.y = cvtpk_bf16(g0.z, g0.w);
      w2.z = cvtpk_bf16(g1.x, g1.y); w2.w = cvtpk_bf16(g1.z, g1.w);
      *(uint4*)(&As[srow + 64][scol]) = w2;
    }
    *(uint4*)(&Bs[srow][scol])      = *(const uint4*)(Bt + (size_t)(cn + srow) * DM_ + k0 + scol);
    *(uint4*)(&Bs[srow + 64][scol]) = *(const uint4*)(Bt + (size_t)(cn + srow + 64) * DM_ + k0 + scol);
    __syncthreads();
    bf16x8 af[4], bfr[4];
#pragma unroll
    for (int m = 0; m < 4; ++m)
      af[m] = *(const bf16x8*)(&As[wr * 64 + m * 16 + l15][l4 * 8]);
#pragma unroll
    for (int n = 0; n < 4; ++n)
      bfr[n] = *(const bf16x8*)(&Bs[wc * 64 + n * 16 + l15][l4 * 8]);
#pragma unroll
    for (int m = 0; m < 4; ++m)
#pragma unroll
      for (int n = 0; n < 4; ++n)
        acc[m][n] = __builtin_amdgcn_mfma_f32_16x16x32_bf16(af[m], bfr[n], acc[m][n], 0, 0, 0);
  }

#pragma unroll
  for (int m = 0; m < 4; ++m)
#pragma unroll
    for (int n = 0; n < 4; ++n) {
      int col = cn + wc * 64 + n * 16 + l15;
      float bv_ = bias[col];
#pragma unroll
      for (int r = 0; r < 4; ++r) {
        int row = rm + wr * 64 + m * 16 + l4 * 4 + r;
        float v = (acc[m][n][r] + bv_) * scale;
        int b = row >> 11, s = row & 2047;
        int h = col >> 6, d = col & 63;
        if (z < 2)
          outp[(((size_t)(b * H_ + h)) * S_ + s) * D_ + d] = f2b(v);
        else
          outp[(((size_t)(b * H_ + h)) * D_ + d) * S_ + s] = f2b(v);
      }
    }
}

// ---------------- output GEMM: out[8192][512] fp32 = ctx bf16 @ Wo^T + bo ----------------
__global__ __launch_bounds__(256) void gemm_out_kernel(
    const u16* __restrict__ A, const u16* __restrict__ Bt,
    const float* __restrict__ bias, float* __restrict__ outp) {
  __shared__ u16 As[64][40];
  __shared__ u16 Bs[128][40];
  const int t = threadIdx.x;
  const int lane = t & 63, w = t >> 6;
  const int l15 = lane & 15, l4 = lane >> 4;
  const int cn = blockIdx.x * 128, rm = blockIdx.y * 64;
  const int srow = t >> 2, scol = (t & 3) << 3;

  f32x4 acc[4][2] = {};

  for (int k0 = 0; k0 < DM_; k0 += 32) {
    __syncthreads();
    *(uint4*)(&As[srow][scol])      = *(const uint4*)(A + (size_t)(rm + srow) * DM_ + k0 + scol);
    *(uint4*)(&Bs[srow][scol])      = *(const uint4*)(Bt + (size_t)(cn + srow) * DM_ + k0 + scol);
    *(uint4*)(&Bs[srow + 64][scol]) = *(const uint4*)(Bt + (size_t)(cn + srow + 64) * DM_ + k0 + scol);
    __syncthreads();
    bf16x8 af[4], bfr[2];
#pragma unroll
    for (int m = 0; m < 4; ++m)
      af[m] = *(const bf16x8*)(&As[m * 16 + l15][l4 * 8]);
#pragma unroll
    for (int n = 0; n < 2; ++n)
      bfr[n] = *(const bf16x8*)(&Bs[w * 32 + n * 16 + l15][l4 * 8]);
#pragma unroll
    for (int m = 0; m < 4; ++m)
#pragma unroll
      for (int n = 0; n < 2; ++n)
        acc[m][n] = __builtin_amdgcn_mfma_f32_16x16x32_bf16(af[m], bfr[n], acc[m][n], 0, 0, 0);
  }

#pragma unroll
  for (int m = 0; m < 4; ++m)
#pragma unroll
    for (int n = 0; n < 2; ++n) {
      int col = cn + w * 32 + n * 16 + l15;
      float bv_ = bias[col];
#pragma unroll
      for (int r = 0; r < 4; ++r) {
        int row = rm + m * 16 + l4 * 4 + r;
        outp[(size_t)row * DM_ + col] = acc[m][n][r] + bv_;
      }
    }
}

// ---------------- flash attention: LDS-staged, split-K2, sgpr lane-mask softmax ----------
__global__ __launch_bounds__(256, 4) void attn_kernel(
    const u16* __restrict__ qp, const u16* __restrict__ kp, const u16* __restrict__ vp,
    const u64* __restrict__ wmask, u16* __restrict__ ctx) {
  __shared__ __align__(16) char smem[32768];  // [0,16K): Kl[2][64][64]; [16K,32K): Vl[2][64][64]
  const int t = threadIdx.x, lane = t & 63, w = t >> 6;
  const int l31 = lane & 31, hi = lane >> 5;
  const int ksub = w & 1, qsub = w >> 1;
  const int wu = __builtin_amdgcn_readfirstlane(w);  // wave-uniform copy for scalar paths
  // XCD-aware remap: one head per XCD (K/V stay L2-resident)
  const int wgid = blockIdx.x;
  const int h = wgid & 7, idx = wgid >> 3;
  const int b = idx >> 5, qt = idx & 31;
  const size_t head  = ((size_t)(b * H_ + h)) * S_ * D_;
  const size_t headT = ((size_t)(b * H_ + h)) * D_ * S_;
  const int q0 = qt * 64 + qsub * 32;
  const int q  = q0 + l31;

  // Q fragments (B-operand): col q = lane&31, k = ks*16 + hi*8 + j
  bf16x8 qf[4];
  {
    const u16* qrow = qp + head + (size_t)q * D_;
#pragma unroll
    for (int ks = 0; ks < 4; ++ks) qf[ks] = *(const bf16x8*)(qrow + ks * 16 + hi * 8);
  }

  // wave-uniform mask pointer: [b][qg][kt][ksub*16 + r]
  const u64* wm = wmask + (((size_t)(b * 64 + qt * 2 + (wu >> 1)) * 32) * 32) + (wu & 1) * 16;

  // LDS read addressing: byte = row*128 + (colbyte ^ ((row&7)<<4))
  const int kxor = (l31 & 7) << 4;
  const int krbase = (ksub * 32 + l31) * 128;
  const int rbase0 = l31 * 128, rbase1 = (32 + l31) * 128;
  int colx[4];
#pragma unroll
  for (int s = 0; s < 4; ++s) colx[s] = ((s * 32 + hi * 16) ^ kxor);
  int vcolx[2];
#pragma unroll
  for (int s = 0; s < 2; ++s) vcolx[s] = ((ksub * 64 + s * 32 + hi * 16) ^ kxor);

  // staging: 4 x gload16 per thread per tile; LDS dest linear, global col pre-swizzled
  const int srow = lane >> 3;
  const int scol = ((lane & 7) ^ srow) << 3;
  const int c0 = w, c1 = w + 4;
  const u16* ksrc0 = kp + head + (size_t)(c0 * 8 + srow) * D_ + scol;
  const u16* ksrc1 = kp + head + (size_t)(c1 * 8 + srow) * D_ + scol;
  const u16* vsrc0 = vp + headT + (size_t)(c0 * 8 + srow) * S_ + scol;
  const u16* vsrc1 = vp + headT + (size_t)(c1 * 8 + srow) * S_ + scol;

  f32x16 accO0, accO1, FZ;
#pragma unroll
  for (int i = 0; i < 16; ++i) { accO0[i] = 0.f; accO1[i] = 0.f; FZ[i] = 0.f; }
  float lrow = 0.f;

  auto stage = [&](int bufi, int kt) {
    char* kb = smem + bufi * 8192;
    char* vb = smem + 16384 + bufi * 8192;
    gload16(ksrc0 + (size_t)kt * 4096, kb + c0 * 1024);
    gload16(ksrc1 + (size_t)kt * 4096, kb + c1 * 1024);
    gload16(vsrc0 + kt * 64, vb + c0 * 1024);
    gload16(vsrc1 + kt * 64, vb + c1 * 1024);
  };

  stage(0, 0);
  __syncthreads();
  int buf = 0;

  for (int kt = 0; kt < S_ / 64; ++kt) {
    if (kt < S_ / 64 - 1) stage(buf ^ 1, kt + 1);
    // scalar lane-predicate masks for this tile (16 x u64, consecutive -> s_load)
    u64 mskr[16];
    {
      const u64* wmk = wm + kt * 32;
#pragma unroll
      for (int r = 0; r < 16; ++r) mskr[r] = wmk[r];
    }

    const char* kb = smem + buf * 8192;
    const char* vb = smem + 16384 + buf * 8192;

    // QK^T swapped: lane holds scores for its q across this wave's 32 keys
    f32x16 s;
    {
      bf16x8 kf[4];
#pragma unroll
      for (int ks = 0; ks < 4; ++ks) kf[ks] = *(const bf16x8*)(kb + krbase + colx[ks]);
      __builtin_amdgcn_s_setprio(1);
      s = __builtin_amdgcn_mfma_f32_32x32x16_bf16(kf[0], qf[0], FZ, 0, 0, 0);
#pragma unroll
      for (int ks = 1; ks < 4; ++ks)
        s = __builtin_amdgcn_mfma_f32_32x32x16_bf16(kf[ks], qf[ks], s, 0, 0, 0);
      __builtin_amdgcn_s_setprio(0);
    }

    // no-max softmax, mask via sgpr-pair cndmask: e = pred ? exp2(s) : 0
    float e[16];
    float rs[4] = {0.f, 0.f, 0.f, 0.f};
#pragma unroll
    for (int r = 0; r < 16; ++r) {
      float em = selmask(exp2fast(s[r]), mskr[r]);
      e[r] = em;
      rs[r & 3] += em;
    }
    float rsum = (rs[0] + rs[1]) + (rs[2] + rs[3]);
    rsum += __shfl_xor(rsum, 32);
    lrow += rsum;

    // P -> MFMA A-fragments in-register: cvt_pk + permlane32_swap
    {
      u32 pw[8];
#pragma unroll
      for (int j = 0; j < 8; ++j)
        pw[j] = cvtpk_bf16(e[2 * j], e[2 * j + 1]);
      plswap(pw[0], pw[2]); plswap(pw[1], pw[3]);
      plswap(pw[4], pw[6]); plswap(pw[5], pw[7]);
      __builtin_amdgcn_s_setprio(1);
#pragma unroll
      for (int s2 = 0; s2 < 2; ++s2) {
        union { u32 wds[4]; bf16x8 v; } pa;
        pa.wds[0] = pw[s2 * 4 + 0]; pa.wds[1] = pw[s2 * 4 + 1];
        pa.wds[2] = pw[s2 * 4 + 2]; pa.wds[3] = pw[s2 * 4 + 3];
        bf16x8 vf0 = *(const bf16x8*)(vb + rbase0 + vcolx[s2]);
        accO0 = __builtin_amdgcn_mfma_f32_32x32x16_bf16(pa.v, vf0, accO0, 0, 0, 0);
        bf16x8 vf1 = *(const bf16x8*)(vb + rbase1 + vcolx[s2]);
        accO1 = __builtin_amdgcn_mfma_f32_32x32x16_bf16(pa.v, vf1, accO1, 0, 0, 0);
      }
      __builtin_amdgcn_s_setprio(0);
    }
    __syncthreads();
    buf ^= 1;
  }

  // ---- split-K combine (aliased onto staging LDS, safe after final barrier) ----
  float (*Ol)[32][64] = (float (*)[32][64])smem;        // [qsub][q][d] 16KB
  float* Ll = (float*)(smem + 16384);                   // [qsub*32+q]
  if (ksub == 1) {
#pragma unroll
    for (int r = 0; r < 16; ++r) {
      const int qr = (r & 3) + 8 * (r >> 2) + 4 * hi;
      Ol[qsub][qr][l31]      = accO0[r];
      Ol[qsub][qr][32 + l31] = accO1[r];
    }
    if (hi == 0) Ll[qsub * 32 + l31] = lrow;
  }
  __syncthreads();
  if (ksub == 0) {
    lrow += Ll[qsub * 32 + l31];
    float inv = 1.0f / lrow;
    float invr[16];
#pragma unroll
    for (int r = 0; r < 16; ++r) invr[r] = __shfl(inv, (r & 3) + 8 * (r >> 2) + 4 * hi);

    const int colA = h * 64 + l31, colB = h * 64 + 32 + l31;
#pragma unroll
    for (int r = 0; r < 16; ++r) {
      const int qr = (r & 3) + 8 * (r >> 2) + 4 * hi;
      const int row = q0 + qr;
      u16* o = ctx + ((size_t)(b * S_) + row) * DM_;
      o[colA] = f2b((accO0[r] + Ol[qsub][qr][l31])      * invr[r]);
      o[colB] = f2b((accO1[r] + Ol[qsub][qr][32 + l31]) * invr[r]);
    }
  }
}

extern "C" void kernel_launch(void* const* d_in, const int* in_sizes, int n_in,
                              void* d_out, int out_size, void* d_ws, size_t ws_size,
                              hipStream_t stream) {
  const float* Q  = (const float*)d_in[0];
  const float* K  = (const float*)d_in[1];
  const float* V  = (const float*)d_in[2];
  const int* mask = (const int*)d_in[3];
  const float* Wq = (const float*)d_in[4];
  const float* bq = (const float*)d_in[5];
  const float* Wk = (const float*)d_in[6];
  const float* bk = (const float*)d_in[7];
  const float* Wv = (const float*)d_in[8];
  const float* bv = (const float*)d_in[9];
  const float* Wo = (const float*)d_in[10];
  const float* bo = (const float*)d_in[11];

  char* ws = (char*)d_ws;
  size_t off = 0;
  auto alloc = [&](size_t bytes) -> void* {
    void* p = ws + off;
    off += (bytes + 255) & ~(size_t)255;
    return p;
  };
  const size_t act_b = (size_t)B_ * S_ * DM_ * 2;
  u16* Wtq = (u16*)alloc((size_t)DM_ * DM_ * 2);
  u16* Wtk = (u16*)alloc((size_t)DM_ * DM_ * 2);
  u16* Wtv = (u16*)alloc((size_t)DM_ * DM_ * 2);
  u16* Wto = (u16*)alloc((size_t)DM_ * DM_ * 2);
  u64* wmask = (u64*)alloc((size_t)B_ * 64 * 32 * 32 * 8);  // 2MB lane-predicate words
  u16* qp  = (u16*)alloc(act_b);
  u16* kp  = (u16*)alloc(act_b);
  u16* vp  = (u16*)alloc(act_b);
  u16* ctx = (u16*)alloc(act_b);

  prep_w_kernel<<<dim3(16, 16, 4), 256, 0, stream>>>(Wq, Wk, Wv, Wo, Wtq, Wtk, Wtv, Wto);
  pack_mask_kernel<<<dim3(8, 64, 4), 256, 0, stream>>>(mask, wmask);

  gemm_qkv_kernel<<<dim3(4, 64, 3), 256, 0, stream>>>(
      Q, K, V, Wtq, Wtk, Wtv, bq, bk, bv, qp, kp, vp);

  attn_kernel<<<dim3(1024), 256, 0, stream>>>(qp, kp, vp, wmask, ctx);

  gemm_out_kernel<<<dim3(4, 128), 256, 0, stream>>>(ctx, Wto, bo, (float*)d_out);
}